// Round 2
// baseline (753.555 us; speedup 1.0000x reference)
//
#include <hip/hip_runtime.h>

typedef __bf16 bf16;
typedef __attribute__((ext_vector_type(8))) __bf16 bf16x8;
typedef __attribute__((ext_vector_type(4))) __bf16 bf16x4;
typedef __attribute__((ext_vector_type(4))) float f32x4;

#define MFMA16(a, b, c) __builtin_amdgcn_mfma_f32_16x16x32_bf16((a), (b), (c), 0, 0, 0)

// ---------------------------------------------------------------------------
// Transpose + fp32->bf16 convert: W[K][N] (row-major) -> Wt[N][K] bf16
// ---------------------------------------------------------------------------
__global__ void transpose_cvt(const float* __restrict__ W, bf16* __restrict__ Wt,
                              int K, int N) {
    __shared__ bf16 tile[32][33];
    int tx = threadIdx.x, ty = threadIdx.y;   // 32 x 8
    int n0 = blockIdx.x * 32, k0 = blockIdx.y * 32;
#pragma unroll
    for (int j = 0; j < 4; ++j)
        tile[ty + j * 8][tx] = (bf16)W[(size_t)(k0 + ty + j * 8) * N + n0 + tx];
    __syncthreads();
#pragma unroll
    for (int j = 0; j < 4; ++j)
        Wt[(size_t)(n0 + ty + j * 8) * K + k0 + tx] = tile[tx][ty + j * 8];
}

// ---------------------------------------------------------------------------
// GEMM: C = A[M][K] * Bt[N][K]^T   (MFMA 16x16x32 bf16, f32 accum)
// OUT_MODE: 0 = bf16 row-major C[m][n]
//           1 = f32 row-major C[m][n]
//           2 = KT layout  Kt[((b*4+hkv)*2048+s)*128+d]   (N=512)
//           3 = VT layout  Vt[((b*4+hkv)*128+d)*2048+s]   (N=512)
// DO_ROPE applies rotary (hd=128, S=2048) + mult by `scale` before store.
// Tiles: 128x128, BK=64, 256 threads = 4 waves, each wave 64x64.
// ---------------------------------------------------------------------------
template <bool A_F32, bool DO_ROPE, int OUT_MODE>
__global__ __launch_bounds__(256) void gemm_bt(
    const void* __restrict__ Ain, const bf16* __restrict__ Bt,
    void* __restrict__ Cout, const float* __restrict__ cosb,
    const float* __restrict__ sinb, float scale, int Mm, int Nn, int Kk) {
    __shared__ bf16 As[128][72];   // +8 pad
    __shared__ bf16 Bs[128][72];
    int tid = threadIdx.x;
    int lane = tid & 63, wid = tid >> 6;
    int lr = lane & 15, lg = lane >> 4;
    int m0 = blockIdx.y * 128, n0 = blockIdx.x * 128;
    int wr = wid >> 1, wc = wid & 1;

    f32x4 acc[4][4] = {};

    const int nk = Kk >> 6;
    for (int kt = 0; kt < nk; ++kt) {
        int k0 = kt << 6;
        if constexpr (A_F32) {
            const float* A = (const float*)Ain;
#pragma unroll
            for (int i = 0; i < 8; ++i) {
                int slot = tid + i * 256;
                int row = slot >> 4, c4 = (slot & 15) << 2;
                f32x4 v = *reinterpret_cast<const f32x4*>(
                    A + (size_t)(m0 + row) * Kk + k0 + c4);
                bf16x4 h;
                h[0] = (bf16)v[0]; h[1] = (bf16)v[1];
                h[2] = (bf16)v[2]; h[3] = (bf16)v[3];
                *reinterpret_cast<bf16x4*>(&As[row][c4]) = h;
            }
        } else {
            const bf16* A = (const bf16*)Ain;
#pragma unroll
            for (int i = 0; i < 4; ++i) {
                int slot = tid + i * 256;
                int row = slot >> 3, c8 = (slot & 7) << 3;
                *reinterpret_cast<bf16x8*>(&As[row][c8]) =
                    *reinterpret_cast<const bf16x8*>(
                        A + (size_t)(m0 + row) * Kk + k0 + c8);
            }
        }
#pragma unroll
        for (int i = 0; i < 4; ++i) {
            int slot = tid + i * 256;
            int row = slot >> 3, c8 = (slot & 7) << 3;
            *reinterpret_cast<bf16x8*>(&Bs[row][c8]) =
                *reinterpret_cast<const bf16x8*>(
                    Bt + (size_t)(n0 + row) * Kk + k0 + c8);
        }
        __syncthreads();
#pragma unroll
        for (int kk = 0; kk < 2; ++kk) {
            bf16x8 af[4], bfr[4];
#pragma unroll
            for (int mi = 0; mi < 4; ++mi)
                af[mi] = *reinterpret_cast<const bf16x8*>(
                    &As[wr * 64 + mi * 16 + lr][kk * 32 + lg * 8]);
#pragma unroll
            for (int ni = 0; ni < 4; ++ni)
                bfr[ni] = *reinterpret_cast<const bf16x8*>(
                    &Bs[wc * 64 + ni * 16 + lr][kk * 32 + lg * 8]);
#pragma unroll
            for (int mi = 0; mi < 4; ++mi)
#pragma unroll
                for (int ni = 0; ni < 4; ++ni)
                    acc[mi][ni] = MFMA16(af[mi], bfr[ni], acc[mi][ni]);
        }
        __syncthreads();
    }

    // ---- epilogue: C/D layout col = lane&15, row = (lane>>4)*4 + r ----
    int m_base = m0 + wr * 64, n_base = n0 + wc * 64;
#pragma unroll
    for (int mi = 0; mi < 4; ++mi) {
#pragma unroll
        for (int ni = 0; ni < 4; ++ni) {
            f32x4 v = acc[mi][ni];
            int gn = n_base + ni * 16 + lr;
            if constexpr (DO_ROPE) {
                int d = gn & 127, p = d >> 1;
                bool ev = ((d & 1) == 0);
#pragma unroll
                for (int r = 0; r < 4; ++r) {
                    int gm = m_base + mi * 16 + lg * 4 + r;
                    int s = gm & 2047;
                    float cc = cosb[s * 64 + p];
                    float ss = sinb[s * 64 + p];
                    float oth = __shfl_xor(v[r], 1);
                    v[r] = (ev ? (v[r] * cc - oth * ss)
                               : (oth * ss + v[r] * cc)) * scale;
                }
            }
            if constexpr (OUT_MODE == 0) {
                bf16* C = (bf16*)Cout;
#pragma unroll
                for (int r = 0; r < 4; ++r)
                    C[(size_t)(m_base + mi * 16 + lg * 4 + r) * Nn + gn] =
                        (bf16)v[r];
            } else if constexpr (OUT_MODE == 1) {
                float* C = (float*)Cout;
#pragma unroll
                for (int r = 0; r < 4; ++r)
                    C[(size_t)(m_base + mi * 16 + lg * 4 + r) * Nn + gn] = v[r];
            } else if constexpr (OUT_MODE == 2) {
                bf16* C = (bf16*)Cout;
                int hkv = gn >> 7, d = gn & 127;
#pragma unroll
                for (int r = 0; r < 4; ++r) {
                    int gm = m_base + mi * 16 + lg * 4 + r;
                    int bb = gm >> 11, s = gm & 2047;
                    C[((size_t)(bb * 4 + hkv) * 2048 + s) * 128 + d] = (bf16)v[r];
                }
            } else {  // OUT_MODE == 3 : VT
                bf16* C = (bf16*)Cout;
                int hkv = gn >> 7, d = gn & 127;
                int gm0 = m_base + mi * 16 + lg * 4;
                int bb = gm0 >> 11, s = gm0 & 2047;
                bf16x4 h;
#pragma unroll
                for (int r = 0; r < 4; ++r) h[r] = (bf16)v[r];
                *reinterpret_cast<bf16x4*>(
                    C + ((size_t)(bb * 4 + hkv) * 128 + d) * 2048 + s) = h;
            }
        }
    }
}

// ---------------------------------------------------------------------------
// Causal flash attention, GQA, barrier-free.
// Qp:(B,S,H,hd) bf16 (pre-scaled by 1/sqrt(hd));
// Kt:(B,HKV,S,hd); Vt:(B,HKV,hd,S)  -- K/V fragments loaded straight from
// global (L2-resident), no K/V LDS staging, no __syncthreads.
// Block = 256 thr = 4 waves, each wave owns 16 q-rows; q-tile = 64 rows.
// KBLK = 64. Grid: (S/64, H, B).
// ---------------------------------------------------------------------------
__global__ __launch_bounds__(256) void attn_kernel(
    const bf16* __restrict__ Qp, const bf16* __restrict__ Kt,
    const bf16* __restrict__ Vt, bf16* __restrict__ Ao) {
    const int S = 2048, H = 16, HKV = 4, HD = 128;
    __shared__ bf16 Plds[4][16][72];   // per-wave P staging (+8 pad)

    int tid = threadIdx.x, lane = tid & 63, wid = tid >> 6;
    int lr = lane & 15, lg = lane >> 4;
    int qt = blockIdx.x, h = blockIdx.y, b = blockIdx.z;
    int hkv = h >> 2;
    int q0 = qt * 64 + wid * 16;

    const bf16* Kbase = Kt + (size_t)(b * HKV + hkv) * S * HD;
    const bf16* Vbase = Vt + (size_t)(b * HKV + hkv) * HD * S;

    // Q fragments: A-layout row=lane&15, k=(lane>>4)*8+j
    bf16x8 qf[4];
    {
        const bf16* qb = Qp + ((size_t)(b * S + q0 + lr) * H + h) * HD;
#pragma unroll
        for (int ks = 0; ks < 4; ++ks)
            qf[ks] = *reinterpret_cast<const bf16x8*>(qb + ks * 32 + lg * 8);
    }

    f32x4 O[8] = {};
    float m_run[4] = {-3e38f, -3e38f, -3e38f, -3e38f};
    float l_run[4] = {0.f, 0.f, 0.f, 0.f};

    for (int kb = 0; kb <= qt; ++kb) {
        int s0 = kb * 64;
        // ---- scores (Q pre-scaled) ----
        float p[4][4];
#pragma unroll
        for (int nt = 0; nt < 4; ++nt) {
            f32x4 sc = {};
            const bf16* krow = Kbase + (size_t)(s0 + nt * 16 + lr) * HD;
#pragma unroll
            for (int ks = 0; ks < 4; ++ks) {
                bf16x8 kf =
                    *reinterpret_cast<const bf16x8*>(krow + ks * 32 + lg * 8);
                sc = MFMA16(qf[ks], kf, sc);
            }
            if (kb == qt) {
                int cs = s0 + nt * 16 + lr;
#pragma unroll
                for (int r = 0; r < 4; ++r)
                    p[nt][r] = (cs <= q0 + lg * 4 + r) ? sc[r] : -1e30f;
            } else {
#pragma unroll
                for (int r = 0; r < 4; ++r) p[nt][r] = sc[r];
            }
        }
        // ---- online softmax (row stats across the 16 lanes of each group) --
        float alpha[4];
#pragma unroll
        for (int r = 0; r < 4; ++r) {
            float mx = fmaxf(fmaxf(p[0][r], p[1][r]), fmaxf(p[2][r], p[3][r]));
#pragma unroll
            for (int off = 1; off < 16; off <<= 1)
                mx = fmaxf(mx, __shfl_xor(mx, off));
            float mnew = fmaxf(m_run[r], mx);
            float al = __expf(m_run[r] - mnew);
            alpha[r] = al;
            m_run[r] = mnew;
            float rs = 0.f;
#pragma unroll
            for (int nt = 0; nt < 4; ++nt) {
                p[nt][r] = __expf(p[nt][r] - mnew);
                rs += p[nt][r];
            }
#pragma unroll
            for (int off = 1; off < 16; off <<= 1) rs += __shfl_xor(rs, off);
            l_run[r] = l_run[r] * al + rs;
        }
        // ---- P -> LDS (C-layout -> A-layout), wave-local ----
#pragma unroll
        for (int nt = 0; nt < 4; ++nt)
#pragma unroll
            for (int r = 0; r < 4; ++r)
                Plds[wid][lg * 4 + r][nt * 16 + lr] = (bf16)p[nt][r];
        // ---- rescale O ----
#pragma unroll
        for (int n2 = 0; n2 < 8; ++n2)
#pragma unroll
            for (int r = 0; r < 4; ++r) O[n2][r] *= alpha[r];
        // ---- PV: O += P * V  (V fragments direct from global Vt) ----
        bf16x8 pa0 = *reinterpret_cast<const bf16x8*>(&Plds[wid][lr][lg * 8]);
        bf16x8 pa1 =
            *reinterpret_cast<const bf16x8*>(&Plds[wid][lr][32 + lg * 8]);
#pragma unroll
        for (int d2 = 0; d2 < 8; ++d2) {
            const bf16* vrow = Vbase + (size_t)(d2 * 16 + lr) * S + s0;
            bf16x8 vf0 = *reinterpret_cast<const bf16x8*>(vrow + lg * 8);
            bf16x8 vf1 = *reinterpret_cast<const bf16x8*>(vrow + 32 + lg * 8);
            O[d2] = MFMA16(pa0, vf0, O[d2]);
            O[d2] = MFMA16(pa1, vf1, O[d2]);
        }
    }

    // ---- epilogue: normalize and store (B,S,H,hd) ----
#pragma unroll
    for (int r = 0; r < 4; ++r) {
        float inv = 1.0f / l_run[r];
        size_t gm = (size_t)(b * S + q0 + lg * 4 + r);
#pragma unroll
        for (int n2 = 0; n2 < 8; ++n2)
            Ao[(gm * H + h) * HD + n2 * 16 + lr] = (bf16)(O[n2][r] * inv);
    }
}

// ---------------------------------------------------------------------------
extern "C" void kernel_launch(void* const* d_in, const int* in_sizes, int n_in,
                              void* d_out, int out_size, void* d_ws,
                              size_t ws_size, hipStream_t stream) {
    const float* q = (const float*)d_in[0];
    const float* k = (const float*)d_in[1];
    const float* v = (const float*)d_in[2];
    // d_in[3] = mask (causal tril; handled analytically)
    const float* fc = (const float*)d_in[4];
    const float* fs = (const float*)d_in[5];
    const float* Wq = (const float*)d_in[6];
    const float* Wk = (const float*)d_in[7];
    const float* Wv = (const float*)d_in[8];
    const float* Wo = (const float*)d_in[9];

    char* ws = (char*)d_ws;
    bf16* Wq_t = (bf16*)(ws + 0);          //  8,388,608 B
    bf16* Wk_t = (bf16*)(ws + 8388608);    //  2,097,152
    bf16* Wv_t = (bf16*)(ws + 10485760);   //  2,097,152
    bf16* Wo_t = (bf16*)(ws + 12582912);   //  8,388,608
    bf16* Qp   = (bf16*)(ws + 20971520);   // 16,777,216
    bf16* Kt   = (bf16*)(ws + 37748736);   //  4,194,304
    bf16* Vt   = (bf16*)(ws + 41943040);   //  4,194,304
    bf16* Ao   = (bf16*)(ws + 46137344);   // 16,777,216  (end 62,914,560)

    dim3 tb(32, 8);
    transpose_cvt<<<dim3(64, 64), tb, 0, stream>>>(Wq, Wq_t, 2048, 2048);
    transpose_cvt<<<dim3(16, 64), tb, 0, stream>>>(Wk, Wk_t, 2048, 512);
    transpose_cvt<<<dim3(16, 64), tb, 0, stream>>>(Wv, Wv_t, 2048, 512);
    transpose_cvt<<<dim3(64, 64), tb, 0, stream>>>(Wo, Wo_t, 2048, 2048);

    const float qscale = 0.08838834764831845f;  // 1/sqrt(128)

    // Q projection + RoPE (scaled) -> Qp (B,S,H,hd)
    gemm_bt<true, true, 0><<<dim3(16, 32), 256, 0, stream>>>(
        (const void*)q, Wq_t, (void*)Qp, fc, fs, qscale, 4096, 2048, 2048);
    // K projection + RoPE -> Kt (B,HKV,S,hd)
    gemm_bt<true, true, 2><<<dim3(4, 32), 256, 0, stream>>>(
        (const void*)k, Wk_t, (void*)Kt, fc, fs, 1.0f, 4096, 512, 2048);
    // V projection -> Vt (B,HKV,hd,S)  (pre-transposed)
    gemm_bt<true, false, 3><<<dim3(4, 32), 256, 0, stream>>>(
        (const void*)v, Wv_t, (void*)Vt, fc, fs, 1.0f, 4096, 512, 2048);

    attn_kernel<<<dim3(32, 16, 2), 256, 0, stream>>>(Qp, Kt, Vt, Ao);

    // Output projection -> d_out fp32
    gemm_bt<false, false, 1><<<dim3(16, 32), 256, 0, stream>>>(
        (const void*)Ao, Wo_t, d_out, fc, fs, 1.0f, 4096, 2048, 2048);
}

// Round 3
// 324.517 us; speedup vs baseline: 2.3221x; 2.3221x over previous
//
#include <hip/hip_runtime.h>

typedef __bf16 bf16;
typedef __attribute__((ext_vector_type(8))) __bf16 bf16x8;
typedef __attribute__((ext_vector_type(4))) __bf16 bf16x4;
typedef __attribute__((ext_vector_type(4))) float f32x4;

#define MFMA16(a, b, c) __builtin_amdgcn_mfma_f32_16x16x32_bf16((a), (b), (c), 0, 0, 0)

// ---------------------------------------------------------------------------
// Transpose + fp32->bf16 convert: W[K][N] (row-major) -> Wt[N][K] bf16
// ---------------------------------------------------------------------------
__global__ void transpose_cvt(const float* __restrict__ W, bf16* __restrict__ Wt,
                              int K, int N) {
    __shared__ bf16 tile[32][33];
    int tx = threadIdx.x, ty = threadIdx.y;   // 32 x 8
    int n0 = blockIdx.x * 32, k0 = blockIdx.y * 32;
#pragma unroll
    for (int j = 0; j < 4; ++j)
        tile[ty + j * 8][tx] = (bf16)W[(size_t)(k0 + ty + j * 8) * N + n0 + tx];
    __syncthreads();
#pragma unroll
    for (int j = 0; j < 4; ++j)
        Wt[(size_t)(n0 + ty + j * 8) * K + k0 + tx] = tile[tx][ty + j * 8];
}

// ---------------------------------------------------------------------------
// GEMM: C = A[M][K] * Bt[N][K]^T   (MFMA 16x16x32 bf16, f32 accum)
// OUT_MODE: 0 = bf16 row-major C[m][n]
//           1 = f32 row-major C[m][n]
//           2 = KT layout  Kt[((b*4+hkv)*2048+s)*128+d]   (N=512)
//           3 = VT layout  Vt[((b*4+hkv)*128+d)*2048+s]   (N=512)
// DO_ROPE applies rotary (hd=128, S=2048) + mult by `scale` before store.
// Tiles: 128x128, BK=64, 256 threads = 4 waves, each wave 64x64.
// ---------------------------------------------------------------------------
template <bool A_F32, bool DO_ROPE, int OUT_MODE>
__global__ __launch_bounds__(256) void gemm_bt(
    const void* __restrict__ Ain, const bf16* __restrict__ Bt,
    void* __restrict__ Cout, const float* __restrict__ cosb,
    const float* __restrict__ sinb, float scale, int Mm, int Nn, int Kk) {
    __shared__ bf16 As[128][72];   // +8 pad
    __shared__ bf16 Bs[128][72];
    int tid = threadIdx.x;
    int lane = tid & 63, wid = tid >> 6;
    int lr = lane & 15, lg = lane >> 4;
    int m0 = blockIdx.y * 128, n0 = blockIdx.x * 128;
    int wr = wid >> 1, wc = wid & 1;

    f32x4 acc[4][4] = {};

    const int nk = Kk >> 6;
    for (int kt = 0; kt < nk; ++kt) {
        int k0 = kt << 6;
        if constexpr (A_F32) {
            const float* A = (const float*)Ain;
#pragma unroll
            for (int i = 0; i < 8; ++i) {
                int slot = tid + i * 256;
                int row = slot >> 4, c4 = (slot & 15) << 2;
                f32x4 v = *reinterpret_cast<const f32x4*>(
                    A + (size_t)(m0 + row) * Kk + k0 + c4);
                bf16x4 h;
                h[0] = (bf16)v[0]; h[1] = (bf16)v[1];
                h[2] = (bf16)v[2]; h[3] = (bf16)v[3];
                *reinterpret_cast<bf16x4*>(&As[row][c4]) = h;
            }
        } else {
            const bf16* A = (const bf16*)Ain;
#pragma unroll
            for (int i = 0; i < 4; ++i) {
                int slot = tid + i * 256;
                int row = slot >> 3, c8 = (slot & 7) << 3;
                *reinterpret_cast<bf16x8*>(&As[row][c8]) =
                    *reinterpret_cast<const bf16x8*>(
                        A + (size_t)(m0 + row) * Kk + k0 + c8);
            }
        }
#pragma unroll
        for (int i = 0; i < 4; ++i) {
            int slot = tid + i * 256;
            int row = slot >> 3, c8 = (slot & 7) << 3;
            *reinterpret_cast<bf16x8*>(&Bs[row][c8]) =
                *reinterpret_cast<const bf16x8*>(
                    Bt + (size_t)(n0 + row) * Kk + k0 + c8);
        }
        __syncthreads();
#pragma unroll
        for (int kk = 0; kk < 2; ++kk) {
            bf16x8 af[4], bfr[4];
#pragma unroll
            for (int mi = 0; mi < 4; ++mi)
                af[mi] = *reinterpret_cast<const bf16x8*>(
                    &As[wr * 64 + mi * 16 + lr][kk * 32 + lg * 8]);
#pragma unroll
            for (int ni = 0; ni < 4; ++ni)
                bfr[ni] = *reinterpret_cast<const bf16x8*>(
                    &Bs[wc * 64 + ni * 16 + lr][kk * 32 + lg * 8]);
#pragma unroll
            for (int mi = 0; mi < 4; ++mi)
#pragma unroll
                for (int ni = 0; ni < 4; ++ni)
                    acc[mi][ni] = MFMA16(af[mi], bfr[ni], acc[mi][ni]);
        }
        __syncthreads();
    }

    // ---- epilogue: C/D layout col = lane&15, row = (lane>>4)*4 + r ----
    int m_base = m0 + wr * 64, n_base = n0 + wc * 64;
#pragma unroll
    for (int mi = 0; mi < 4; ++mi) {
#pragma unroll
        for (int ni = 0; ni < 4; ++ni) {
            f32x4 v = acc[mi][ni];
            int gn = n_base + ni * 16 + lr;
            if constexpr (DO_ROPE) {
                int d = gn & 127, p = d >> 1;
                bool ev = ((d & 1) == 0);
#pragma unroll
                for (int r = 0; r < 4; ++r) {
                    int gm = m_base + mi * 16 + lg * 4 + r;
                    int s = gm & 2047;
                    float cc = cosb[s * 64 + p];
                    float ss = sinb[s * 64 + p];
                    float oth = __shfl_xor(v[r], 1);
                    v[r] = (ev ? (v[r] * cc - oth * ss)
                               : (oth * ss + v[r] * cc)) * scale;
                }
            }
            if constexpr (OUT_MODE == 0) {
                bf16* C = (bf16*)Cout;
#pragma unroll
                for (int r = 0; r < 4; ++r)
                    C[(size_t)(m_base + mi * 16 + lg * 4 + r) * Nn + gn] =
                        (bf16)v[r];
            } else if constexpr (OUT_MODE == 1) {
                float* C = (float*)Cout;
#pragma unroll
                for (int r = 0; r < 4; ++r)
                    C[(size_t)(m_base + mi * 16 + lg * 4 + r) * Nn + gn] = v[r];
            } else if constexpr (OUT_MODE == 2) {
                bf16* C = (bf16*)Cout;
                int hkv = gn >> 7, d = gn & 127;
#pragma unroll
                for (int r = 0; r < 4; ++r) {
                    int gm = m_base + mi * 16 + lg * 4 + r;
                    int bb = gm >> 11, s = gm & 2047;
                    C[((size_t)(bb * 4 + hkv) * 2048 + s) * 128 + d] = (bf16)v[r];
                }
            } else {  // OUT_MODE == 3 : VT
                bf16* C = (bf16*)Cout;
                int hkv = gn >> 7, d = gn & 127;
                int gm0 = m_base + mi * 16 + lg * 4;
                int bb = gm0 >> 11, s = gm0 & 2047;
                bf16x4 h;
#pragma unroll
                for (int r = 0; r < 4; ++r) h[r] = (bf16)v[r];
                *reinterpret_cast<bf16x4*>(
                    C + ((size_t)(bb * 4 + hkv) * 128 + d) * 2048 + s) = h;
            }
        }
    }
}

// ---------------------------------------------------------------------------
// Causal flash attention, GQA.
// Qp:(B,S,H,hd) bf16 (pre-scaled by 1/sqrt(hd));
// Kt:(B,HKV,S,hd); Vt:(B,HKV,hd,S).
// K/V tiles staged in padded LDS (pure vector copy, no transpose needed).
// Block = 256 thr = 4 waves, each wave 16 q-rows; q-tile = 64; KBLK = 64.
// Grid: (H, B, S/64) with qt = last - blockIdx.z  (heavy-first / LPT order).
// ---------------------------------------------------------------------------
__global__ __launch_bounds__(256) void attn_kernel(
    const bf16* __restrict__ Qp, const bf16* __restrict__ Kt,
    const bf16* __restrict__ Vt, bf16* __restrict__ Ao) {
    const int S = 2048, H = 16, HKV = 4, HD = 128;
    __shared__ bf16 Klds[64][136];     // [s][d], +8 pad (stride = 4 banks)
    __shared__ bf16 Vlds[128][72];     // [d][s], +8 pad
    __shared__ bf16 Plds[4][16][72];   // per-wave P staging

    int tid = threadIdx.x, lane = tid & 63, wid = tid >> 6;
    int lr = lane & 15, lg = lane >> 4;
    int h = blockIdx.x, b = blockIdx.y;
    int qt = (int)(gridDim.z - 1) - (int)blockIdx.z;   // heavy blocks first
    int hkv = h >> 2;
    int q0 = qt * 64 + wid * 16;

    const bf16* Kbase = Kt + (size_t)(b * HKV + hkv) * S * HD;
    const bf16* Vbase = Vt + (size_t)(b * HKV + hkv) * HD * S;

    // Q fragments: A-layout row=lane&15, k=(lane>>4)*8+j
    bf16x8 qf[4];
    {
        const bf16* qb = Qp + ((size_t)(b * S + q0 + lr) * H + h) * HD;
#pragma unroll
        for (int ks = 0; ks < 4; ++ks)
            qf[ks] = *reinterpret_cast<const bf16x8*>(qb + ks * 32 + lg * 8);
    }

    // staging coordinates (fixed per thread)
    f32x4 O[8] = {};
    float m_run[4] = {-3e38f, -3e38f, -3e38f, -3e38f};
    float l_run[4] = {0.f, 0.f, 0.f, 0.f};

    for (int kb = 0; kb <= qt; ++kb) {
        int s0 = kb * 64;
        // ---- stage K (64 x 128) and V (128 x 64) tiles, vectorized ----
        bf16x8 kreg[4], vreg[4];
#pragma unroll
        for (int i = 0; i < 4; ++i) {
            int slot = tid + i * 256;
            int krow = slot >> 4, kc = (slot & 15) << 3;
            kreg[i] = *reinterpret_cast<const bf16x8*>(
                Kbase + (size_t)(s0 + krow) * HD + kc);
            int vrow = slot >> 3, vc = (slot & 7) << 3;
            vreg[i] = *reinterpret_cast<const bf16x8*>(
                Vbase + (size_t)vrow * S + s0 + vc);
        }
#pragma unroll
        for (int i = 0; i < 4; ++i) {
            int slot = tid + i * 256;
            int krow = slot >> 4, kc = (slot & 15) << 3;
            *reinterpret_cast<bf16x8*>(&Klds[krow][kc]) = kreg[i];
            int vrow = slot >> 3, vc = (slot & 7) << 3;
            *reinterpret_cast<bf16x8*>(&Vlds[vrow][vc]) = vreg[i];
        }
        __syncthreads();

        // ---- scores: S = Q K^T  (Q pre-scaled by 1/sqrt(hd)) ----
        float p[4][4];
#pragma unroll
        for (int nt = 0; nt < 4; ++nt) {
            f32x4 sc = {};
#pragma unroll
            for (int ks = 0; ks < 4; ++ks) {
                bf16x8 kf = *reinterpret_cast<const bf16x8*>(
                    &Klds[nt * 16 + lr][ks * 32 + lg * 8]);
                sc = MFMA16(qf[ks], kf, sc);
            }
            if (kb == qt) {
                int cs = s0 + nt * 16 + lr;
#pragma unroll
                for (int r = 0; r < 4; ++r)
                    p[nt][r] = (cs <= q0 + lg * 4 + r) ? sc[r] : -1e30f;
            } else {
#pragma unroll
                for (int r = 0; r < 4; ++r) p[nt][r] = sc[r];
            }
        }
        // ---- online softmax (row stats across 16 lanes of each group) ----
        float alpha[4];
#pragma unroll
        for (int r = 0; r < 4; ++r) {
            float mx = fmaxf(fmaxf(p[0][r], p[1][r]), fmaxf(p[2][r], p[3][r]));
#pragma unroll
            for (int off = 1; off < 16; off <<= 1)
                mx = fmaxf(mx, __shfl_xor(mx, off));
            float mnew = fmaxf(m_run[r], mx);
            float al = __expf(m_run[r] - mnew);
            alpha[r] = al;
            m_run[r] = mnew;
            float rs = 0.f;
#pragma unroll
            for (int nt = 0; nt < 4; ++nt) {
                p[nt][r] = __expf(p[nt][r] - mnew);
                rs += p[nt][r];
            }
#pragma unroll
            for (int off = 1; off < 16; off <<= 1) rs += __shfl_xor(rs, off);
            l_run[r] = l_run[r] * al + rs;
        }
        // ---- P -> LDS (C-layout -> A-layout), wave-local ----
#pragma unroll
        for (int nt = 0; nt < 4; ++nt)
#pragma unroll
            for (int r = 0; r < 4; ++r)
                Plds[wid][lg * 4 + r][nt * 16 + lr] = (bf16)p[nt][r];
        // ---- rescale O ----
#pragma unroll
        for (int n2 = 0; n2 < 8; ++n2)
#pragma unroll
            for (int r = 0; r < 4; ++r) O[n2][r] *= alpha[r];
        // ---- PV: O += P * V ----
        bf16x8 pa0 = *reinterpret_cast<const bf16x8*>(&Plds[wid][lr][lg * 8]);
        bf16x8 pa1 =
            *reinterpret_cast<const bf16x8*>(&Plds[wid][lr][32 + lg * 8]);
#pragma unroll
        for (int d2 = 0; d2 < 8; ++d2) {
            bf16x8 vf0 =
                *reinterpret_cast<const bf16x8*>(&Vlds[d2 * 16 + lr][lg * 8]);
            bf16x8 vf1 = *reinterpret_cast<const bf16x8*>(
                &Vlds[d2 * 16 + lr][32 + lg * 8]);
            O[d2] = MFMA16(pa0, vf0, O[d2]);
            O[d2] = MFMA16(pa1, vf1, O[d2]);
        }
        __syncthreads();
    }

    // ---- epilogue: normalize and store (B,S,H,hd) ----
#pragma unroll
    for (int r = 0; r < 4; ++r) {
        float inv = 1.0f / l_run[r];
        size_t gm = (size_t)(b * S + q0 + lg * 4 + r);
#pragma unroll
        for (int n2 = 0; n2 < 8; ++n2)
            Ao[(gm * H + h) * HD + n2 * 16 + lr] = (bf16)(O[n2][r] * inv);
    }
}

// ---------------------------------------------------------------------------
extern "C" void kernel_launch(void* const* d_in, const int* in_sizes, int n_in,
                              void* d_out, int out_size, void* d_ws,
                              size_t ws_size, hipStream_t stream) {
    const float* q = (const float*)d_in[0];
    const float* k = (const float*)d_in[1];
    const float* v = (const float*)d_in[2];
    // d_in[3] = mask (causal tril; handled analytically)
    const float* fc = (const float*)d_in[4];
    const float* fs = (const float*)d_in[5];
    const float* Wq = (const float*)d_in[6];
    const float* Wk = (const float*)d_in[7];
    const float* Wv = (const float*)d_in[8];
    const float* Wo = (const float*)d_in[9];

    char* ws = (char*)d_ws;
    bf16* Wq_t = (bf16*)(ws + 0);          //  8,388,608 B
    bf16* Wk_t = (bf16*)(ws + 8388608);    //  2,097,152
    bf16* Wv_t = (bf16*)(ws + 10485760);   //  2,097,152
    bf16* Wo_t = (bf16*)(ws + 12582912);   //  8,388,608
    bf16* Qp   = (bf16*)(ws + 20971520);   // 16,777,216
    bf16* Kt   = (bf16*)(ws + 37748736);   //  4,194,304
    bf16* Vt   = (bf16*)(ws + 41943040);   //  4,194,304
    bf16* Ao   = (bf16*)(ws + 46137344);   // 16,777,216  (end 62,914,560)

    dim3 tb(32, 8);
    transpose_cvt<<<dim3(64, 64), tb, 0, stream>>>(Wq, Wq_t, 2048, 2048);
    transpose_cvt<<<dim3(16, 64), tb, 0, stream>>>(Wk, Wk_t, 2048, 512);
    transpose_cvt<<<dim3(16, 64), tb, 0, stream>>>(Wv, Wv_t, 2048, 512);
    transpose_cvt<<<dim3(64, 64), tb, 0, stream>>>(Wo, Wo_t, 2048, 2048);

    const float qscale = 0.08838834764831845f;  // 1/sqrt(128)

    // Q projection + RoPE (scaled) -> Qp (B,S,H,hd)
    gemm_bt<true, true, 0><<<dim3(16, 32), 256, 0, stream>>>(
        (const void*)q, Wq_t, (void*)Qp, fc, fs, qscale, 4096, 2048, 2048);
    // K projection + RoPE -> Kt (B,HKV,S,hd)
    gemm_bt<true, true, 2><<<dim3(4, 32), 256, 0, stream>>>(
        (const void*)k, Wk_t, (void*)Kt, fc, fs, 1.0f, 4096, 512, 2048);
    // V projection -> Vt (B,HKV,hd,S)  (pre-transposed)
    gemm_bt<true, false, 3><<<dim3(4, 32), 256, 0, stream>>>(
        (const void*)v, Wv_t, (void*)Vt, fc, fs, 1.0f, 4096, 512, 2048);

    // heavy-first (LPT) over q-tiles: grid (H, B, S/64)
    attn_kernel<<<dim3(16, 2, 32), 256, 0, stream>>>(Qp, Kt, Vt, Ao);

    // Output projection -> d_out fp32
    gemm_bt<false, false, 1><<<dim3(16, 32), 256, 0, stream>>>(
        (const void*)Ao, Wo_t, d_out, fc, fs, 1.0f, 4096, 2048, 2048);
}